// Round 6
// baseline (88.892 us; speedup 1.0000x reference)
//
#include <hip/hip_runtime.h>
#include <hip/hip_bf16.h>
#include <math.h>

#define B_    16
#define P_    25
#define D_SL_ 32
#define H_    320
#define W_    320
#define BP    400
#define KPIX  4096
#define FOUT  1280
#define HID   128
#define NG    3

#define M_PAD    512
#define KSPL     8
#define CH_STEPS 16          // 32-wide k-steps per k-chunk (512 k per chunk)

typedef __attribute__((ext_vector_type(8))) short  bf16x8;
typedef __attribute__((ext_vector_type(8))) ushort u16x8;
typedef __attribute__((ext_vector_type(4))) float  f32x4;
typedef __attribute__((ext_vector_type(4))) unsigned int u32x4;
typedef unsigned long long ull;

// ws byte offsets
#define OFF_APH  0ull
#define OFF_APL  4194304ull      // 128*512*32*2
#define OFF_PART 8388608ull
#define WS_NEED  (8388608ull + (ull)KSPL * BP * FOUT * 4ull)

__device__ inline void split_bf16(float x, ushort& hi, ushort& lo) {
    __hip_bfloat16 h = __float2bfloat16(x);
    float hf = __bfloat162float(h);
    __hip_bfloat16 l = __float2bfloat16(x - hf);
    hi = *(ushort*)&h;
    lo = *(ushort*)&l;
}

// ---------------- crops -> panels [step][M_PAD][32] (r4-proven pattern) ----------------
__global__ __launch_bounds__(256) void crops_prep(
    const float* __restrict__ images,
    const float* __restrict__ z_pred,
    const float* __restrict__ xy_pred,
    ushort* __restrict__ APH, ushort* __restrict__ APL)
{
    __shared__ float S[64][65];
    int t = threadIdx.x;
    int pt = blockIdx.x;
    if (pt >= BP) {
        u16x8 z8 = (u16x8)0;
        #pragma unroll
        for (int i = 0; i < 2; ++i) {
            int tau = t + i * 256;
            int step = tau >> 2, q = tau & 3;
            *(u16x8*)(APH + ((size_t)step * M_PAD + pt) * 32 + q * 8) = z8;
            *(u16x8*)(APL + ((size_t)step * M_PAD + pt) * 32 + q * 8) = z8;
        }
        return;
    }
    int b = pt / P_;
    int z = (int)rintf(z_pred[pt] - 1.0f);
    z = min(max(z, 0), D_SL_ - 1);
    int x = (int)rintf(4.0f * xy_pred[pt * 2 + 0]);
    int y = (int)rintf(4.0f * xy_pred[pt * 2 + 1]);
    x = min(max(x, 0), W_ - 1);
    y = min(max(y, 0), H_ - 1);
    const float* img = images + (size_t)(b * D_SL_ + z) * (H_ * W_);

    #pragma unroll
    for (int i = 0; i < 16; ++i) {
        int idx = t + i * 256;
        int r = idx >> 6, c = idx & 63;
        int iy = y - 32 + r, ix = x - 32 + c;
        float v = 0.0f;
        if ((unsigned)iy < (unsigned)H_ && (unsigned)ix < (unsigned)W_)
            v = img[iy * W_ + ix];
        S[r][c] = v;
    }
    __syncthreads();

    #pragma unroll
    for (int i = 0; i < 2; ++i) {
        int tau = t + i * 256;
        int step = tau >> 2, q = tau & 3;
        int r = step >> 1, cb = (step & 1) * 32 + q * 8;
        u16x8 vh, vl;
        #pragma unroll
        for (int e = 0; e < 8; ++e) {
            ushort hi, lo;
            split_bf16(S[r][cb + e], hi, lo);
            vh[e] = hi; vl[e] = lo;
        }
        *(u16x8*)(APH + ((size_t)step * M_PAD + pt) * 32 + q * 8) = vh;
        *(u16x8*)(APL + ((size_t)step * M_PAD + pt) * 32 + q * 8) = vl;
    }
}

// ---------------- GEMM, W read direct from HBM (prep_w fused in) ----------------
// grid: id = kz + 8*ntile (160 blocks); block = 512 thr (8 waves).
// Block covers M=512 (full), N=64, K-chunk=512. Each W_feat element is read by
// exactly one block (f32, 3 channels summed + split-bf16 on the fly).
// A-chunk per kz = 1MB -> L2-resident on its XCD (kz = id&7 swizzle).
__global__ __launch_bounds__(512) void gemm_direct(
    const ushort* __restrict__ APH, const ushort* __restrict__ APL,
    const float* __restrict__ Wf,
    float* __restrict__ part, float* __restrict__ out0)
{
    __shared__ ushort Atile[512 * 64];   // 64 KB
    __shared__ ushort Btile[64 * 64];    // 8 KB

    int t = threadIdx.x;
    int id = blockIdx.x;
    int kz = id & 7;
    int n0 = (id >> 3) * 64;
    int stepbase = kz * CH_STEPS;

    if (id == 0 && t == 0) out0[0] = 0.0f;

    int w = t >> 6, l = t & 63;
    int l16 = l & 15, kg = l >> 4;

    f32x4 acc[4][4];
    #pragma unroll
    for (int i = 0; i < 4; ++i)
        #pragma unroll
        for (int j = 0; j < 4; ++j) acc[i][j] = (f32x4){0.f, 0.f, 0.f, 0.f};

    // A staging: thread t owns panel row t (hi+lo). B: thread owns (n=t&63, 4 k's).
    int rmA = t & 15;
    int bn = t & 63, bkq = (t >> 6) << 2;
    int rmB = bn & 15;

    u32x4 pa[8];
    ull pbh, pbl;

#define LOADS(s_)                                                                   \
    {                                                                               \
        size_t sa = ((size_t)(stepbase + (s_)) * M_PAD + t) * 32;                   \
        const u32x4* ah_ = (const u32x4*)(APH + sa);                                \
        const u32x4* al_ = (const u32x4*)(APL + sa);                                \
        pa[0] = ah_[0]; pa[1] = ah_[1]; pa[2] = ah_[2]; pa[3] = ah_[3];             \
        pa[4] = al_[0]; pa[5] = al_[1]; pa[6] = al_[2]; pa[7] = al_[3];             \
        const float* wb = Wf + (size_t)((stepbase + (s_)) * 32 + bkq) * FOUT        \
                          + n0 + bn;                                                \
        ushort hs[4], ls[4];                                                        \
        _Pragma("unroll")                                                           \
        for (int i_ = 0; i_ < 4; ++i_) {                                            \
            const float* p_ = wb + (size_t)i_ * FOUT;                               \
            float v_ = p_[0] + p_[(size_t)KPIX * FOUT] + p_[(size_t)2 * KPIX * FOUT];\
            split_bf16(v_, hs[i_], ls[i_]);                                         \
        }                                                                           \
        pbh = *(ull*)hs; pbl = *(ull*)ls;                                           \
    }

    LOADS(0);
    for (int s = 0; s < CH_STEPS; ++s) {
        __syncthreads();
        {
            // A: row t, units j=0..7 hi, 8..15 lo, u = j ^ (row&15)
            ushort* arow = &Atile[t * 64];
            #pragma unroll
            for (int q = 0; q < 4; ++q) {
                #pragma unroll
                for (int h = 0; h < 2; ++h) {
                    int j = q * 2 + h;
                    *(ull*)&arow[(j ^ rmA) * 4] = ((const ull*)&pa[q])[h];
                    *(ull*)&arow[((j + 8) ^ rmA) * 4] = ((const ull*)&pa[4 + q])[h];
                }
            }
            // B: row bn, hi unit bkq/4, lo unit 8+bkq/4
            ushort* brow = &Btile[bn * 64];
            *(ull*)&brow[(((bkq >> 2)) ^ rmB) * 4] = pbh;
            *(ull*)&brow[((8 + (bkq >> 2)) ^ rmB) * 4] = pbl;
        }
        __syncthreads();
        if (s + 1 < CH_STEPS) LOADS(s + 1);

        union FragU { ull q[2]; bf16x8 v; };
        bf16x8 ah[4], al[4], bh[4], bl[4];
        #pragma unroll
        for (int mi = 0; mi < 4; ++mi) {
            int r = w * 64 + mi * 16 + l16;
            const ushort* rowp = &Atile[r * 64];
            FragU fh, fl;
            fh.q[0] = *(const ull*)&rowp[(((2 * kg) ^ l16)) * 4];
            fh.q[1] = *(const ull*)&rowp[(((2 * kg + 1) ^ l16)) * 4];
            fl.q[0] = *(const ull*)&rowp[(((8 + 2 * kg) ^ l16)) * 4];
            fl.q[1] = *(const ull*)&rowp[(((9 + 2 * kg) ^ l16)) * 4];
            ah[mi] = fh.v; al[mi] = fl.v;
        }
        #pragma unroll
        for (int ni = 0; ni < 4; ++ni) {
            int r = ni * 16 + l16;
            const ushort* rowp = &Btile[r * 64];
            FragU fh, fl;
            fh.q[0] = *(const ull*)&rowp[(((2 * kg) ^ l16)) * 4];
            fh.q[1] = *(const ull*)&rowp[(((2 * kg + 1) ^ l16)) * 4];
            fl.q[0] = *(const ull*)&rowp[(((8 + 2 * kg) ^ l16)) * 4];
            fl.q[1] = *(const ull*)&rowp[(((9 + 2 * kg) ^ l16)) * 4];
            bh[ni] = fh.v; bl[ni] = fl.v;
        }
        #pragma unroll
        for (int mi = 0; mi < 4; ++mi)
            #pragma unroll
            for (int ni = 0; ni < 4; ++ni) {
                acc[mi][ni] = __builtin_amdgcn_mfma_f32_16x16x32_bf16(ah[mi], bh[ni], acc[mi][ni], 0, 0, 0);
                acc[mi][ni] = __builtin_amdgcn_mfma_f32_16x16x32_bf16(ah[mi], bl[ni], acc[mi][ni], 0, 0, 0);
                acc[mi][ni] = __builtin_amdgcn_mfma_f32_16x16x32_bf16(al[mi], bh[ni], acc[mi][ni], 0, 0, 0);
            }
    }
#undef LOADS

    #pragma unroll
    for (int mi = 0; mi < 4; ++mi)
        #pragma unroll
        for (int ni = 0; ni < 4; ++ni)
            #pragma unroll
            for (int r = 0; r < 4; ++r) {
                int m = w * 64 + mi * 16 + kg * 4 + r;
                if (m < BP) {
                    int n = n0 + ni * 16 + l16;
                    part[((size_t)kz * BP + m) * FOUT + n] = acc[mi][ni][r];
                }
            }
}

// ---------------- MLP + softmax + fused loss (r5-proven) ----------------
__global__ __launch_bounds__(512) void mlp4_loss(
    const float* __restrict__ part,
    const float* __restrict__ bfeat,
    const float* __restrict__ W1, const float* __restrict__ b1,
    const float* __restrict__ W2, const float* __restrict__ b2,
    const int* __restrict__ grade,
    float* __restrict__ probs, float* __restrict__ out0)
{
    __shared__ float sf[4][FOUT];
    __shared__ float shp[4][4][HID];
    __shared__ float sh[4][HID];
    __shared__ float sl[4][NG];
    __shared__ float sden[512];
    int r0 = blockIdx.x * 4;
    int t = threadIdx.x;

    float dwt = 0.0f;
    if (t < BP) {
        int g = grade[t];
        dwt = (g == 0) ? 1.0f : (g == 1 ? 2.0f : 4.0f);
    }
    sden[t] = dwt;

    for (int i = t; i < 4 * FOUT; i += 512) {
        int r = i / FOUT, c = i - r * FOUT;
        size_t base = (size_t)(r0 + r) * FOUT + c;
        float v = bfeat[c];
        #pragma unroll
        for (int kzi = 0; kzi < KSPL; ++kzi)
            v += part[(size_t)kzi * BP * FOUT + base];
        sf[r][c] = v;
    }
    __syncthreads();
    for (int s = 256; s > 0; s >>= 1) {
        if (t < s) sden[t] += sden[t + s];
        __syncthreads();
    }
    float den = sden[0];

    {
        int kh = t >> 7, j = t & 127;
        float a0 = (kh == 0) ? b1[j] : 0.0f, a1 = 0.0f, a2 = 0.0f, a3 = 0.0f;
        const float* wp = W1 + (size_t)(kh * 320) * HID + j;
        const float* s0 = &sf[0][kh * 320];
        const float* s1 = &sf[1][kh * 320];
        const float* s2 = &sf[2][kh * 320];
        const float* s3 = &sf[3][kh * 320];
        #pragma unroll 8
        for (int k = 0; k < 320; ++k) {
            float wv = wp[(size_t)k * HID];
            a0 = fmaf(s0[k], wv, a0);
            a1 = fmaf(s1[k], wv, a1);
            a2 = fmaf(s2[k], wv, a2);
            a3 = fmaf(s3[k], wv, a3);
        }
        shp[kh][0][j] = a0;
        shp[kh][1][j] = a1;
        shp[kh][2][j] = a2;
        shp[kh][3][j] = a3;
    }
    __syncthreads();
    {
        int rr = t >> 7, j = t & 127;
        sh[rr][j] = fmaxf(shp[0][rr][j] + shp[1][rr][j] + shp[2][rr][j] + shp[3][rr][j], 0.0f);
    }
    __syncthreads();
    if (t < 12) {
        int rr = t / 3, c = t - rr * 3;
        float a = b2[c];
        #pragma unroll 16
        for (int k = 0; k < HID; ++k) a = fmaf(sh[rr][k], W2[k * NG + c], a);
        sl[rr][c] = a;
    }
    __syncthreads();
    if (t < 4) {
        float l0 = sl[t][0], l1 = sl[t][1], l2 = sl[t][2];
        float m = fmaxf(l0, fmaxf(l1, l2));
        float e0 = expf(l0 - m), e1 = expf(l1 - m), e2 = expf(l2 - m);
        float inv = 1.0f / (e0 + e1 + e2);
        int row = r0 + t;
        probs[row * NG + 0] = e0 * inv;
        probs[row * NG + 1] = e1 * inv;
        probs[row * NG + 2] = e2 * inv;

        int g = grade[row];
        float lv = (g == 0) ? l0 : (g == 1 ? l1 : l2);
        lv = fminf(fmaxf(lv, 1e-5f), 1.0f - 1e-5f);
        float wt = (g == 0) ? 1.0f : (g == 1 ? 2.0f : 4.0f);
        atomicAdd(out0, -(wt * logf(lv)) / den);
    }
}

// ---------------- launch ----------------
extern "C" void kernel_launch(void* const* d_in, const int* in_sizes, int n_in,
                              void* d_out, int out_size, void* d_ws, size_t ws_size,
                              hipStream_t stream) {
    const float* images  = (const float*)d_in[0];
    const float* z_pred  = (const float*)d_in[1];
    const float* xy_pred = (const float*)d_in[2];
    const int*   grade   = (const int*)d_in[3];
    const float* W_feat  = (const float*)d_in[4];
    const float* b_feat  = (const float*)d_in[5];
    const float* W1      = (const float*)d_in[6];
    const float* b1      = (const float*)d_in[7];
    const float* W2      = (const float*)d_in[8];
    const float* b2      = (const float*)d_in[9];

    float* out = (float*)d_out;
    char* w = (char*)d_ws;
    ushort* APH = (ushort*)(w + OFF_APH);
    ushort* APL = (ushort*)(w + OFF_APL);
    float*  part = (float*)(w + OFF_PART);

    crops_prep<<<M_PAD, 256, 0, stream>>>(images, z_pred, xy_pred, APH, APL);
    gemm_direct<<<20 * KSPL, 512, 0, stream>>>(APH, APL, W_feat, part, out);
    mlp4_loss<<<BP / 4, 512, 0, stream>>>(part, b_feat, W1, b1, W2, b2, grade, out + 1, out);
}